// Round 8
// baseline (522.463 us; speedup 1.0000x reference)
//
#include <hip/hip_runtime.h>
#include <math.h>

#define NEG_SLOPE 0.2f

typedef _Float16 half8 __attribute__((ext_vector_type(8)));
typedef _Float16 half4 __attribute__((ext_vector_type(4)));
typedef _Float16 half2v __attribute__((ext_vector_type(2)));
typedef float    f32x4 __attribute__((ext_vector_type(4)));
typedef float    fvec4 __attribute__((ext_vector_type(4)));
typedef float    fvec2 __attribute__((ext_vector_type(2)));

// ---------------- CSR build ----------------
__global__ void k_count(const int* __restrict__ dst, int E, int N, int* __restrict__ cnt){
  int i = blockIdx.x*blockDim.x + threadIdx.x;
  if (i < E) atomicAdd(&cnt[dst[i]], 1);
  else if (i < E + N) atomicAdd(&cnt[i - E], 1);   // self loops
}

__global__ void k_scan_block(const int* __restrict__ cnt, int* __restrict__ ex,
                             int* __restrict__ bsum, int N){
  __shared__ int tmp[256];
  int t = threadIdx.x;
  int i = blockIdx.x*256 + t;
  int v = (i < N) ? cnt[i] : 0;
  tmp[t] = v; __syncthreads();
  for (int off = 1; off < 256; off <<= 1){
    int u = (t >= off) ? tmp[t-off] : 0;
    __syncthreads();
    tmp[t] += u;
    __syncthreads();
  }
  if (i < N) ex[i] = tmp[t] - v;
  if (t == 255) bsum[blockIdx.x] = tmp[255];
}

__global__ void k_scan_tops(int* __restrict__ bsum, int nb){
  __shared__ int tmp[256];
  int t = threadIdx.x;
  int v = (t < nb) ? bsum[t] : 0;
  tmp[t] = v; __syncthreads();
  for (int off = 1; off < 256; off <<= 1){
    int u = (t >= off) ? tmp[t-off] : 0;
    __syncthreads();
    tmp[t] += u;
    __syncthreads();
  }
  if (t < nb) bsum[t] = tmp[t] - v;
}

__global__ void k_scan_add(int* __restrict__ row_start, const int* __restrict__ bsum,
                           int N, int total){
  int i = blockIdx.x*256 + threadIdx.x;
  if (i < N) row_start[i] += bsum[blockIdx.x];
  if (i == 0) row_start[N] = total;
}

__global__ void k_scatter(const int* __restrict__ src, const int* __restrict__ dst,
                          int E, int N, const int* __restrict__ row_start,
                          int* __restrict__ cursor, int* __restrict__ edge_src){
  int i = blockIdx.x*blockDim.x + threadIdx.x;
  if (i < E){
    int d = dst[i];
    int p = atomicAdd(&cursor[d], 1);
    edge_src[row_start[d] + p] = src[i];
  } else if (i < E + N){
    int n = i - E;
    int p = atomicAdd(&cursor[n], 1);
    edge_src[row_start[n] + p] = n;
  }
}

// ---------------- W split: W[K][Nw] fp32 -> WT[Nw][2K] f16 rows [Wh(K)|Wl(K)] ----------------
__global__ void k_splitW(const float* __restrict__ W, _Float16* __restrict__ WT,
                         int K, int Nw){
  int id = blockIdx.x*blockDim.x + threadIdx.x;
  if (id >= K*Nw) return;
  int n = id / K, k = id % K;
  float w = W[(size_t)k*Nw + n];
  _Float16 h = (_Float16)w;
  _Float16 l = (_Float16)(w - (float)h);
  size_t base = (size_t)n*2*K;
  WT[base + k]     = h;
  WT[base + K + k] = l;
}

// ---------------- x split: x[N][K] fp32 -> X16[N][2K] f16 rows [xh(K)|xl(K)] ----------------
__global__ void k_split_x(const float* __restrict__ x, _Float16* __restrict__ X16,
                          int N, int K){
  int id = blockIdx.x*blockDim.x + threadIdx.x;
  int per = K/8;
  if (id >= N*per) return;
  int rr = id / per, c = (id % per)*8;
  fvec4 f0 = *(const fvec4*)&x[(size_t)rr*K + c];
  fvec4 f1 = *(const fvec4*)&x[(size_t)rr*K + c + 4];
  half8 hh, hl;
  #pragma unroll
  for (int q = 0; q < 4; ++q){
    _Float16 h0 = (_Float16)f0[q];
    hh[q] = h0; hl[q] = (_Float16)(f0[q] - (float)h0);
    _Float16 h1 = (_Float16)f1[q];
    hh[4+q] = h1; hl[4+q] = (_Float16)(f1[q] - (float)h1);
  }
  *(half8*)&X16[(size_t)rr*2*K + c]     = hh;
  *(half8*)&X16[(size_t)rr*2*K + K + c] = hl;
}

// ---------------- split-f16 MFMA GEMM: BK=32, 36KB LDS, 4 blocks/CU ----------------
// [XL|XR] = A @ [Wl|Wr] + bias, A16 rows = [Ah(K)|Al(K)], WT rows = [Wh(K)|Wl(K)].
// Per 32-chunk: stage Ah,Al,Wh,Wl 128x32 tiles (stride 36); 48 MFMA between barriers.
#define LSTR 36
__global__ __launch_bounds__(256, 4)
void k_gemm_split(const _Float16* __restrict__ A16, const _Float16* __restrict__ WT,
                  const float* __restrict__ biasL, const float* __restrict__ biasR,
                  _Float16* __restrict__ XL, _Float16* __restrict__ XR,
                  int M, int K, int NwHalf, int gy, int qq, int rr){
  __shared__ _Float16 sAh[128*LSTR];
  __shared__ _Float16 sAl[128*LSTR];
  __shared__ _Float16 sWh[128*LSTR];
  __shared__ _Float16 sWl[128*LSTR];
  const int tid  = threadIdx.x;
  const int lane = tid & 63;
  const int wid  = tid >> 6;
  const int wm   = wid >> 1, wn = wid & 1;

  // bijective xcd-chunked remap: consecutive logical blocks share one XCD
  const int h   = blockIdx.x;
  const int xcd = h & 7, idx = h >> 3;
  const int l   = xcd*qq + (xcd < rr ? xcd : rr) + idx;
  const int bx  = l / gy, by = l - bx*gy;
  const int m0  = bx * 128;
  const int n0  = by * 128;
  const int lda = 2*K;

  f32x4 acc[4][4];
  #pragma unroll
  for (int i = 0; i < 4; ++i)
    #pragma unroll
    for (int j = 0; j < 4; ++j)
      acc[i][j] = (f32x4){0.f,0.f,0.f,0.f};

  const int l15 = lane & 15;
  const int lhi = lane >> 4;

  const int nc = K/32;
  for (int c = 0; c < nc; ++c){
    const int kA = c*32;
    #pragma unroll
    for (int it = 0; it < 2; ++it){
      int idx2 = it*256 + tid;          // 0..511
      int r = idx2 >> 2, c8 = idx2 & 3; // 128 rows x 4 col-groups of 8 halves
      int gr = m0 + r;
      half8 vh = (half8)(_Float16)0.f, vl = (half8)(_Float16)0.f;
      if (gr < M){
        vh = *(const half8*)&A16[(size_t)gr*lda + kA + c8*8];
        vl = *(const half8*)&A16[(size_t)gr*lda + K + kA + c8*8];
      }
      *(half8*)&sAh[r*LSTR + c8*8] = vh;
      *(half8*)&sAl[r*LSTR + c8*8] = vl;
      int wr = n0 + r;
      *(half8*)&sWh[r*LSTR + c8*8] = *(const half8*)&WT[(size_t)wr*lda + kA + c8*8];
      *(half8*)&sWl[r*LSTR + c8*8] = *(const half8*)&WT[(size_t)wr*lda + K + kA + c8*8];
    }
    __syncthreads();
    {
      half8 ah[4], al[4], bh[4], bl[4];
      #pragma unroll
      for (int fm = 0; fm < 4; ++fm){
        ah[fm] = *(const half8*)&sAh[(wm*64 + fm*16 + l15)*LSTR + 8*lhi];
        al[fm] = *(const half8*)&sAl[(wm*64 + fm*16 + l15)*LSTR + 8*lhi];
      }
      #pragma unroll
      for (int fn = 0; fn < 4; ++fn){
        bh[fn] = *(const half8*)&sWh[(wn*64 + fn*16 + l15)*LSTR + 8*lhi];
        bl[fn] = *(const half8*)&sWl[(wn*64 + fn*16 + l15)*LSTR + 8*lhi];
      }
      #pragma unroll
      for (int fm = 0; fm < 4; ++fm)
        #pragma unroll
        for (int fn = 0; fn < 4; ++fn)
          acc[fm][fn] = __builtin_amdgcn_mfma_f32_16x16x32_f16(ah[fm], bh[fn], acc[fm][fn], 0, 0, 0);
      #pragma unroll
      for (int fm = 0; fm < 4; ++fm)
        #pragma unroll
        for (int fn = 0; fn < 4; ++fn)
          acc[fm][fn] = __builtin_amdgcn_mfma_f32_16x16x32_f16(al[fm], bh[fn], acc[fm][fn], 0, 0, 0);
      #pragma unroll
      for (int fm = 0; fm < 4; ++fm)
        #pragma unroll
        for (int fn = 0; fn < 4; ++fn)
          acc[fm][fn] = __builtin_amdgcn_mfma_f32_16x16x32_f16(ah[fm], bl[fn], acc[fm][fn], 0, 0, 0);
    }
    __syncthreads();
  }
  const bool isR = (n0 >= NwHalf);
  const float* bias = isR ? biasR : biasL;
  _Float16* Xo = isR ? XR : XL;
  const int nbase = isR ? (n0 - NwHalf) : n0;
  #pragma unroll
  for (int fm = 0; fm < 4; ++fm){
    #pragma unroll
    for (int fn = 0; fn < 4; ++fn){
      int cc = nbase + wn*64 + fn*16 + l15;
      float bv = bias[cc];
      #pragma unroll
      for (int q = 0; q < 4; ++q){
        int row = m0 + wm*64 + fm*16 + lhi*4 + q;
        if (row < M) Xo[(size_t)row*NwHalf + cc] = (_Float16)(acc[fm][fn][q] + bv);
      }
    }
  }
}

// ---------------- GATv2 aggregation v4: edge-slot split wave ----------------
template<int HC, int C, int SPLIT>
__global__ __launch_bounds__(256) void k_gat_agg(const _Float16* __restrict__ xl,
                                                 const _Float16* __restrict__ xr,
                                                 const float* __restrict__ att,
                                                 const float* __restrict__ bias,
                                                 const int* __restrict__ row_start,
                                                 const int* __restrict__ edge_src,
                                                 void* __restrict__ outp,
                                                 int N, int apply_elu){
  constexpr int VEC   = 8;
  constexpr int LPE   = HC/VEC;    // lanes per edge (32 or 16)
  constexpr int EPW   = 64/LPE;    // edge slots per wave (2 or 4)
  constexpr int GROUP = C/VEC;     // lanes per head (8 or 16)
  const float M_INIT = -1.0e30f, T_INACT = -2.0e30f, THR = 11.54f; // ~8 nats

  int wid = (int)(((size_t)blockIdx.x * blockDim.x + threadIdx.x) >> 6);
  int lane = threadIdx.x & 63;
  if (wid >= N) return;
  const int h  = lane / LPE;                       // edge slot
  const int li = lane % LPE;
  const int ch = (li/GROUP)*C + (li%GROUP)*VEC;    // my channel base

  const _Float16 s16 = (_Float16)NEG_SLOPE;
  const half2v slope2 = {s16, s16};

  half2v attv2[4], xrr2[4];
  {
    fvec4 a0 = *(const fvec4*)&att[ch];
    fvec4 a1 = *(const fvec4*)&att[ch+4];
    const float L2E = 1.4426950408889634f;
    attv2[0][0]=(_Float16)(a0[0]*L2E); attv2[0][1]=(_Float16)(a0[1]*L2E);
    attv2[1][0]=(_Float16)(a0[2]*L2E); attv2[1][1]=(_Float16)(a0[3]*L2E);
    attv2[2][0]=(_Float16)(a1[0]*L2E); attv2[2][1]=(_Float16)(a1[1]*L2E);
    attv2[3][0]=(_Float16)(a1[2]*L2E); attv2[3][1]=(_Float16)(a1[3]*L2E);
    half8 hv = *(const half8*)&xr[(unsigned)(wid*HC) + ch];
    #pragma unroll
    for (int p = 0; p < 4; ++p){ xrr2[p][0] = hv[2*p]; xrr2[p][1] = hv[2*p+1]; }
  }

  float acc[VEC];
  #pragma unroll
  for (int q = 0; q < VEC; ++q) acc[q] = 0.f;
  float m = M_INIT, s = 0.f;

  const int e0   = row_start[wid];
  const int ecnt = row_start[wid+1] - e0;
  const _Float16* xlb = xl + ch;

  auto rowload = [&](int sn)->half8 {
    return *(const half8*)(xlb + (unsigned)(sn*HC));
  };
  auto logit1 = [&](half8 x8)->float{
    float t = 0.f;
    #pragma unroll
    for (int p = 0; p < 4; ++p){
      half2v xp; xp[0] = x8[2*p]; xp[1] = x8[2*p+1];
      half2v v  = xp + xrr2[p];
      half2v lv = __builtin_elementwise_max(v, v*slope2);   // leaky relu
      t = __builtin_amdgcn_fdot2(lv, attv2[p], t, false);
    }
    #pragma unroll
    for (int off = GROUP/2; off > 0; off >>= 1)
      t += __shfl_xor(t, off, 64);
    return t;
  };
  auto update2 = [&](float ta, float tb, half8 xa, half8 xb){
    float pm = fmaxf(ta, tb);
    if (__all(pm <= m + THR)){
      float pa = __builtin_amdgcn_exp2f(ta - m);
      float pb = __builtin_amdgcn_exp2f(tb - m);
      s += pa + pb;
      #pragma unroll
      for (int q = 0; q < VEC; ++q)
        acc[q] = fmaf(pa, (float)xa[q], fmaf(pb, (float)xb[q], acc[q]));
    } else {
      float nm = fmaxf(pm, m);
      float wo = __builtin_amdgcn_exp2f(m - nm);
      float pa = __builtin_amdgcn_exp2f(ta - nm);
      float pb = __builtin_amdgcn_exp2f(tb - nm);
      s = fmaf(s, wo, pa + pb);
      m = nm;
      #pragma unroll
      for (int q = 0; q < VEC; ++q)
        acc[q] = fmaf(pa, (float)xa[q], fmaf(pb, (float)xb[q], acc[q]*wo));
    }
  };

  int base = e0 + h;
  const int R = ecnt / (2*EPW);
  for (int r = 0; r < R; ++r, base += 2*EPW){
    int sa = edge_src[base];
    int sb = edge_src[base + EPW];
    half8 xa = rowload(sa);
    half8 xb = rowload(sb);
    float ta = logit1(xa);
    float tb = logit1(xb);
    update2(ta, tb, xa, xb);
  }
  if (2*EPW*R < ecnt){               // predicated tail pair (uniform branch)
    const int last = e0 + ecnt;
    bool a1 = base < last, a2 = base + EPW < last;
    int sa = a1 ? edge_src[base] : 0;
    int sb = a2 ? edge_src[base + EPW] : 0;
    half8 xa = rowload(sa);
    half8 xb = rowload(sb);
    float ta = logit1(xa); ta = a1 ? ta : T_INACT;
    float tb = logit1(xb); tb = a2 ? tb : T_INACT;
    update2(ta, tb, xa, xb);
  }

  // merge edge-slot states (lanes ±LPE hold same channels)
  #pragma unroll
  for (int off = LPE; off < 64; off <<= 1){
    float mo = __shfl_xor(m, off, 64);
    float so = __shfl_xor(s, off, 64);
    float M  = fmaxf(m, mo);
    float w  = __builtin_amdgcn_exp2f(m  - M);
    float wo = __builtin_amdgcn_exp2f(mo - M);
    s = s*w + so*wo;
    #pragma unroll
    for (int q = 0; q < VEC; ++q)
      acc[q] = acc[q]*w + __shfl_xor(acc[q], off, 64)*wo;
    m = M;
  }

  if (h == 0){
    float inv = 1.f / s;
    fvec4 b0 = *(const fvec4*)&bias[ch];
    fvec4 b1 = *(const fvec4*)&bias[ch+4];
    float ov[VEC];
    #pragma unroll
    for (int q = 0; q < VEC; ++q){
      float o = acc[q]*inv + (q < 4 ? b0[q] : b1[q-4]);
      if (apply_elu) o = (o > 0.f) ? o : (__expf(o) - 1.f);
      ov[q] = o;
    }
    if constexpr (SPLIT){
      _Float16* o16 = (_Float16*)outp;
      half8 hh, hl;
      #pragma unroll
      for (int q = 0; q < VEC; ++q){
        _Float16 hv = (_Float16)ov[q];
        hh[q] = hv; hl[q] = (_Float16)(ov[q] - (float)hv);
      }
      *(half8*)&o16[(unsigned)(wid*2*HC) + ch]      = hh;
      *(half8*)&o16[(unsigned)(wid*2*HC) + HC + ch] = hl;
    } else {
      float* o32 = (float*)outp;
      *(fvec4*)&o32[(unsigned)(wid*HC) + ch]     = (fvec4){ov[0],ov[1],ov[2],ov[3]};
      *(fvec4*)&o32[(unsigned)(wid*HC) + ch + 4] = (fvec4){ov[4],ov[5],ov[6],ov[7]};
    }
  }
}

// ---------------- global mean pool ----------------
__global__ void k_pool(const float* __restrict__ h, const int* __restrict__ batch,
                       float* __restrict__ pool, int* __restrict__ gcnt, int N){
  int wid = (int)(((size_t)blockIdx.x * blockDim.x + threadIdx.x) >> 6);
  int lane = threadIdx.x & 63;
  if (wid >= N) return;
  int g = batch[wid];
  #pragma unroll
  for (int j = 0; j < 2; ++j)
    atomicAdd(&pool[(size_t)g*128 + j*64 + lane], h[(size_t)wid*128 + j*64 + lane]);
  if (lane == 0) atomicAdd(&gcnt[g], 1);
}

__global__ void k_pool_div(const float* __restrict__ pool, const int* __restrict__ gcnt,
                           float* __restrict__ out, int total){
  int i = blockIdx.x*blockDim.x + threadIdx.x;
  if (i < total) out[i] = pool[i] / fmaxf((float)gcnt[i >> 7], 1.f);
}

extern "C" void kernel_launch(void* const* d_in, const int* in_sizes, int n_in,
                              void* d_out, int out_size, void* d_ws, size_t ws_size,
                              hipStream_t stream){
  const float* x    = (const float*)d_in[0];
  const int*   ei   = (const int*)  d_in[1];
  const int*   batch= (const int*)  d_in[2];
  const float* Wl1  = (const float*)d_in[3];
  const float* bl1  = (const float*)d_in[4];
  const float* Wr1  = (const float*)d_in[5];
  const float* br1  = (const float*)d_in[6];
  const float* att1 = (const float*)d_in[7];
  const float* b1   = (const float*)d_in[8];
  const float* Wl2  = (const float*)d_in[9];
  const float* bl2  = (const float*)d_in[10];
  const float* Wr2  = (const float*)d_in[11];
  const float* br2  = (const float*)d_in[12];
  const float* att2 = (const float*)d_in[13];
  const float* b2   = (const float*)d_in[14];
  const float* Wl3  = (const float*)d_in[15];
  const float* bl3  = (const float*)d_in[16];
  const float* Wr3  = (const float*)d_in[17];
  const float* br3  = (const float*)d_in[18];
  const float* att3 = (const float*)d_in[19];
  const float* b3   = (const float*)d_in[20];

  int N  = in_sizes[2];          // 50000
  int E  = in_sizes[1] / 2;      // 800000
  int NG = out_size / 128;       // 1000
  const int* esrc = ei;
  const int* edst = ei + E;
  int Mpad = ((N + 127)/128)*128;

  size_t off = 0;
  char* base = (char*)d_ws;
  auto alloc = [&](size_t bytes)->void*{
    void* p = base + off;
    off += (bytes + 255) & ~(size_t)255;
    return p;
  };
  _Float16* XL  = (_Float16*)alloc((size_t)Mpad*256*sizeof(_Float16));
  _Float16* XR  = (_Float16*)alloc((size_t)Mpad*256*sizeof(_Float16));
  _Float16* Hsp = (_Float16*)alloc((size_t)Mpad*512*sizeof(_Float16)); // [Hh|Hl]
  _Float16* X16 = (_Float16*)alloc((size_t)Mpad*128*sizeof(_Float16)); // [xh|xl]
  float*    Hb32= (float*)   alloc((size_t)Mpad*128*sizeof(float));    // layer-3 out
  _Float16* WT  = (_Float16*)alloc((size_t)512*512*sizeof(_Float16));
  int* row_start = (int*)alloc(((size_t)N+1)*sizeof(int));
  int* edge_src  = (int*)alloc((size_t)(E+N)*sizeof(int));
  int* cnt       = (int*)alloc((size_t)N*sizeof(int));
  int* bsum      = (int*)alloc(256*sizeof(int));
  float* pool    = (float*)alloc((size_t)NG*128*sizeof(float));
  int* gcnt      = (int*)alloc((size_t)NG*sizeof(int));
  (void)ws_size; (void)n_in;

  int EN = E + N;
  int nb = (N + 255) / 256;

  // CSR build
  hipMemsetAsync(cnt, 0, (size_t)N*sizeof(int), stream);
  k_count<<<(EN+255)/256, 256, 0, stream>>>(edst, E, N, cnt);
  k_scan_block<<<nb, 256, 0, stream>>>(cnt, row_start, bsum, N);
  k_scan_tops<<<1, 256, 0, stream>>>(bsum, nb);
  k_scan_add<<<nb, 256, 0, stream>>>(row_start, bsum, N, EN);
  hipMemsetAsync(cnt, 0, (size_t)N*sizeof(int), stream);
  k_scatter<<<(EN+255)/256, 256, 0, stream>>>(esrc, edst, E, N, row_start, cnt, edge_src);

  dim3 blk(256);
  int agg_blocks = (N + 3) / 4;
  int gx = Mpad/128;             // 391
  int G1 = gx*4;                 // layers 1,2: 512 cols
  int G3 = gx*2;                 // layer 3: 256 cols

  // ---- Layer 1: K=64 -> 4x64 ----
  k_splitW<<<(64*256+255)/256, blk, 0, stream>>>(Wl1, WT,           64, 256);
  k_splitW<<<(64*256+255)/256, blk, 0, stream>>>(Wr1, WT + 256*128, 64, 256);
  k_split_x<<<((N*8)+255)/256, blk, 0, stream>>>(x, X16, N, 64);
  k_gemm_split<<<G1, blk, 0, stream>>>(X16, WT, bl1, br1, XL, XR, N, 64, 256, 4, G1/8, G1%8);
  k_gat_agg<256,64,1><<<agg_blocks, blk, 0, stream>>>(XL, XR, att1, b1, row_start, edge_src, Hsp, N, 1);

  // ---- Layer 2: K=256 -> 4x64 ----
  k_splitW<<<(256*256+255)/256, blk, 0, stream>>>(Wl2, WT,           256, 256);
  k_splitW<<<(256*256+255)/256, blk, 0, stream>>>(Wr2, WT + 256*512, 256, 256);
  k_gemm_split<<<G1, blk, 0, stream>>>(Hsp, WT, bl2, br2, XL, XR, N, 256, 256, 4, G1/8, G1%8);
  k_gat_agg<256,64,1><<<agg_blocks, blk, 0, stream>>>(XL, XR, att2, b2, row_start, edge_src, Hsp, N, 1);

  // ---- Layer 3: K=256 -> 128, 1 head, no concat, no elu ----
  k_splitW<<<(256*128+255)/256, blk, 0, stream>>>(Wl3, WT,           256, 128);
  k_splitW<<<(256*128+255)/256, blk, 0, stream>>>(Wr3, WT + 128*512, 256, 128);
  k_gemm_split<<<G3, blk, 0, stream>>>(Hsp, WT, bl3, br3, XL, XR, N, 256, 128, 2, G3/8, G3%8);
  k_gat_agg<128,128,0><<<agg_blocks, blk, 0, stream>>>(XL, XR, att3, b3, row_start, edge_src, Hb32, N, 0);

  // ---- Global mean pool ----
  hipMemsetAsync(pool, 0, (size_t)NG*128*sizeof(float), stream);
  hipMemsetAsync(gcnt, 0, (size_t)NG*sizeof(int), stream);
  k_pool<<<agg_blocks, blk, 0, stream>>>(Hb32, batch, pool, gcnt, N);
  k_pool_div<<<(NG*128+255)/256, 256, 0, stream>>>(pool, gcnt, (float*)d_out, NG*128);
}